// Round 5
// baseline (474.156 us; speedup 1.0000x reference)
//
#include <hip/hip_runtime.h>

// GQA (B=2,S=2048,E=2048,H=32,G=8,D=64), softmax over HEAD axis.
// R5: R4 dataflow (swapped QK, P in regs, DPP head-sums, cross-g LDS reduce)
// plus: raw s_barrier with lgkm-only drain (global prefetch survives
// barriers), K double-buffered in regs, raw v_exp_f32, v_cvt_pk_bf16_f32
// packing, QK scale folded into K-proj GEMM epilogue, single fused cvt kernel.

typedef unsigned short u16;
typedef unsigned int u32;
typedef __attribute__((ext_vector_type(8))) __bf16 bf16x8;
typedef __attribute__((ext_vector_type(4))) float f32x4;
typedef __attribute__((ext_vector_type(4))) float float4_t;

#define GLD16(ldsp, gp)                                                  \
  __builtin_amdgcn_global_load_lds(                                      \
      (__attribute__((address_space(1))) void*)(void*)(gp),              \
      (__attribute__((address_space(3))) void*)(void*)(ldsp), 16, 0, 0)

static __device__ __forceinline__ u16 f2bf(float f) {
  union { float f; u32 u; } v; v.f = f;
  u32 u = v.u;
  u32 r = (u + 0x7fffu + ((u >> 16) & 1u)) >> 16;  // RNE
  return (u16)r;
}

static __device__ __forceinline__ bf16x8 ld8(const u16* p) {
  return *(const bf16x8*)p;
}

#if __has_builtin(__builtin_amdgcn_exp2f)
static __device__ __forceinline__ float fexp2(float x) {
  return __builtin_amdgcn_exp2f(x);
}
#else
static __device__ __forceinline__ float fexp2(float x) {
  float r;
  asm("v_exp_f32 %0, %1\n\ts_nop 0" : "=v"(r) : "v"(x));
  return r;
}
#endif

// pack two f32 -> bf16x2 word (lo from a, hi from b), RNE
static __device__ __forceinline__ u32 cvtpk(float a, float b) {
  u32 r;
  asm("v_cvt_pk_bf16_f32 %0, %1, %2" : "=v"(r) : "v"(a), "v"(b));
  return r;
}

// producer-side barrier: make LDS writes visible without draining vmcnt
static __device__ __forceinline__ void barrier_lgkm() {
  asm volatile("s_waitcnt lgkmcnt(0)" ::: "memory");
  __builtin_amdgcn_s_barrier();
  asm volatile("" ::: "memory");
}

// sum over the 4 stride-4 lanes within each 16-lane row (head levels)
static __device__ __forceinline__ float hsum4(float v) {
  v += __builtin_bit_cast(float, __builtin_amdgcn_update_dpp(
           0, __builtin_bit_cast(int, v), 0x124, 0xf, 0xf, true));  // row_ror:4
  v += __builtin_bit_cast(float, __builtin_amdgcn_update_dpp(
           0, __builtin_bit_cast(int, v), 0x128, 0xf, 0xf, true));  // row_ror:8
  return v;
}

// ---------------- fused fp32 -> bf16 for all 5 tensors ----------------
// segment sizes in 8-elem units (compile-time): x 1048576, wq 524288,
// wk 131072, wv 131072, wo 524288; total 2359296.
__global__ void cvt_all(const float* __restrict__ x, const float* __restrict__ wq,
                        const float* __restrict__ wk, const float* __restrict__ wv,
                        const float* __restrict__ wo, u16* __restrict__ xb,
                        u16* __restrict__ wqb, u16* __restrict__ wkb,
                        u16* __restrict__ wvb, u16* __restrict__ wob) {
  int i = blockIdx.x * blockDim.x + threadIdx.x;
  const int stride = gridDim.x * blockDim.x;
  for (; i < 2359296; i += stride) {
    const float* src;
    u16* dst;
    int j;
    if (i < 1048576)      { src = x;  dst = xb;  j = i; }
    else if (i < 1572864) { src = wq; dst = wqb; j = i - 1048576; }
    else if (i < 1703936) { src = wk; dst = wkb; j = i - 1572864; }
    else if (i < 1835008) { src = wv; dst = wvb; j = i - 1703936; }
    else                  { src = wo; dst = wob; j = i - 1835008; }
    const float4_t* p = (const float4_t*)src + (size_t)j * 2;
    float4_t a = p[0], b = p[1];
    u32 w0 = (u32)f2bf(a[0]) | ((u32)f2bf(a[1]) << 16);
    u32 w1 = (u32)f2bf(a[2]) | ((u32)f2bf(a[3]) << 16);
    u32 w2 = (u32)f2bf(b[0]) | ((u32)f2bf(b[1]) << 16);
    u32 w3 = (u32)f2bf(b[2]) | ((u32)f2bf(b[3]) << 16);
    *(uint4*)(dst + (size_t)j * 8) = make_uint4(w0, w1, w2, w3);
  }
}

// ---------------- GEMM: C[M,N] = (A[M,K] @ W[N,K]^T + bias) * scale --------
// MODE 0: bf16 row-major; 1: f32 row-major; 2: bf16 transposed per-batch
// Vt2[b*512+col][s] with k-interleave within each 32-s block.
template <int MODE>
__global__ __launch_bounds__(256, 2)
void gemm_bt(const u16* __restrict__ A, const u16* __restrict__ Bw,
             const float* __restrict__ bias,
             u16* __restrict__ Cb, float* __restrict__ Cf, int N, float scale) {
  constexpr int K = 2048;
  constexpr int SHSZ = (MODE == 2) ? (128 * 136) : 8192;
  __shared__ u16 sh[SHSZ];
  u16* As = sh;
  u16* Bs = sh + 4096;
  const int tid = threadIdx.x;
  const int lane = tid & 63;
  const int w = tid >> 6;
  const int m0 = blockIdx.y * 128;
  const int n0 = blockIdx.x * 128;
  const int wr = (w >> 1) * 64, wc = (w & 1) * 64;
  const int r15 = lane & 15, kq = lane >> 4;

  f32x4 acc[4][4] = {};

  for (int k0 = 0; k0 < K; k0 += 32) {
#pragma unroll
    for (int i = 0; i < 2; ++i) {
      int c = i * 256 + tid;
      int r = c >> 2, ch = c & 3;
      int sc = (ch ^ (r & 3)) * 8;
      GLD16(&As[c * 8], &A[(size_t)(m0 + r) * K + k0 + sc]);
      GLD16(&Bs[c * 8], &Bw[(size_t)(n0 + r) * K + k0 + sc]);
    }
    __syncthreads();
    bf16x8 af[4], bfr[4];
#pragma unroll
    for (int mt = 0; mt < 4; ++mt) {
      int r = wr + mt * 16 + r15;
      af[mt] = ld8(&As[r * 32 + ((kq ^ (r15 & 3)) * 8)]);
    }
#pragma unroll
    for (int nt = 0; nt < 4; ++nt) {
      int r = wc + nt * 16 + r15;
      bfr[nt] = ld8(&Bs[r * 32 + ((kq ^ (r15 & 3)) * 8)]);
    }
#pragma unroll
    for (int mt = 0; mt < 4; ++mt)
#pragma unroll
      for (int nt = 0; nt < 4; ++nt)
        acc[mt][nt] = __builtin_amdgcn_mfma_f32_16x16x32_bf16(af[mt], bfr[nt], acc[mt][nt], 0, 0, 0);
    __syncthreads();
  }

  if constexpr (MODE == 2) {
    // transpose epilogue: C-tile -> LDS [col][136], then k-interleaved write
#pragma unroll
    for (int mt = 0; mt < 4; ++mt)
#pragma unroll
      for (int nt = 0; nt < 4; ++nt) {
        int col = wc + nt * 16 + r15;
        float bv = bias[n0 + col];
#pragma unroll
        for (int r = 0; r < 4; ++r) {
          int row = wr + mt * 16 + kq * 4 + r;
          sh[col * 136 + row] = f2bf(acc[mt][nt][r] + bv);
        }
      }
    __syncthreads();
    const int m0l = m0 & 2047;
    const int bb = m0 >> 11;
#pragma unroll
    for (int i = 0; i < 8; ++i) {
      int c = i * 256 + tid;
      int cc = c >> 4, so = c & 15;
      int X = cc * 136 + (so >> 2) * 32 + (so & 3) * 4;
      u32 A0 = *(const u32*)&sh[X + 0];
      u32 A1 = *(const u32*)&sh[X + 2];
      u32 B0 = *(const u32*)&sh[X + 16];
      u32 B1 = *(const u32*)&sh[X + 18];
      u32 w0 = __builtin_amdgcn_perm(B0, A0, 0x05040100u);
      u32 w1 = __builtin_amdgcn_perm(B0, A0, 0x07060302u);
      u32 w2 = __builtin_amdgcn_perm(B1, A1, 0x05040100u);
      u32 w3 = __builtin_amdgcn_perm(B1, A1, 0x07060302u);
      *(uint4*)&Cb[(size_t)(bb * 512 + n0 + cc) * 2048 + m0l + so * 8] =
          make_uint4(w0, w1, w2, w3);
    }
  } else {
    const int rb = kq * 4;
#pragma unroll
    for (int mt = 0; mt < 4; ++mt) {
#pragma unroll
      for (int nt = 0; nt < 4; ++nt) {
        int col = n0 + wc + nt * 16 + r15;
        float bv = bias[col];
#pragma unroll
        for (int r = 0; r < 4; ++r) {
          int row = m0 + wr + mt * 16 + rb + r;
          float v = (acc[mt][nt][r] + bv) * scale;
          if constexpr (MODE == 0) Cb[(size_t)row * N + col] = f2bf(v);
          else                     Cf[(size_t)row * N + col] = v;
        }
      }
    }
  }
}

// ---------------- fused attention (R5) ----------------
// 16 waves = (g = w&7, zd = w>>3). Per 32-k tile:
//   QK mfma(K,Q) [K pre-scaled by 0.125*log2e] -> v_exp -> DPP 4-head sums
//   -> slab write | lgkm-barrier | cross-g reduce -> rsb | lgkm-barrier |
//   cvt_pk pack P -> PV mfma. K double-buffered in regs (prefetch survives
//   barriers since lgkmcnt doesn't count global loads); V issued post-QK,
//   consumed post-B2.
__global__ __launch_bounds__(1024, 4)
void attn_fused(const u16* __restrict__ Q, const u16* __restrict__ Kg,
                const u16* __restrict__ Vt, u16* __restrict__ O) {
  __shared__ float slab[8 * 528];  // [g][q*33 + k]
  __shared__ float rsb[16 * 36];   // [q][k] 1/sum

  const int tid = threadIdx.x;
  const int lane = tid & 63, w = tid >> 6;
  const int g = w & 7, zd = w >> 3;
  const int l15 = lane & 15, kq = lane >> 4;
  const int qr = l15 & 3, hl = l15 >> 2;

  const int xcd = blockIdx.x & 7;
  const int b = xcd >> 2;
  const int q0 = ((((blockIdx.x >> 3) << 2) + (xcd & 3)) << 4);
  const int qbase = q0 + zd * 8;

  const u16* Qb = Q + (size_t)b * 2048 * 2048;
  const u16* Kb = Kg + (size_t)b * 2048 * 512;
  const u16* Vb = Vt + (size_t)b * 512 * 2048;  // k-interleaved Vt2

  bf16x8 qf[2][2];
#pragma unroll
  for (int qq = 0; qq < 2; ++qq)
#pragma unroll
    for (int t = 0; t < 2; ++t)
      qf[qq][t] = ld8(&Qb[(size_t)(qbase + qq * 4 + qr) * 2048 +
                          (g + 8 * hl) * 64 + t * 32 + kq * 8]);

  f32x4 acc[2][4] = {};
  bf16x8 kfA[2][2], kfB[2][2];

  // preload K tile 0
#pragma unroll
  for (int ko = 0; ko < 2; ++ko)
#pragma unroll
    for (int t = 0; t < 2; ++t)
      kfA[ko][t] = ld8(&Kb[(size_t)(ko * 16 + l15) * 512 + g * 64 + t * 32 + kq * 8]);

  auto tilestep = [&](int k0, bf16x8 (&kfC)[2][2], bf16x8 (&kfN)[2][2]) {
    // ---- QK (swapped): sc[qq][ko] -> e[k = kq*4+reg][hq = r15] ----
    f32x4 sc[2][2];
#pragma unroll
    for (int qq = 0; qq < 2; ++qq)
#pragma unroll
      for (int ko = 0; ko < 2; ++ko) {
        f32x4 s = {};
        s = __builtin_amdgcn_mfma_f32_16x16x32_bf16(kfC[ko][0], qf[qq][0], s, 0, 0, 0);
        s = __builtin_amdgcn_mfma_f32_16x16x32_bf16(kfC[ko][1], qf[qq][1], s, 0, 0, 0);
        sc[qq][ko] = s;
      }

    // ---- prefetch next K tile (stays in flight across barriers) ----
    const int kn = (k0 + 32) & 2047;
#pragma unroll
    for (int ko = 0; ko < 2; ++ko)
#pragma unroll
      for (int t = 0; t < 2; ++t)
        kfN[ko][t] = ld8(&Kb[(size_t)(kn + ko * 16 + l15) * 512 + g * 64 + t * 32 + kq * 8]);

    // ---- V for this tile (latency covered by exp+barriers+reduce) ----
    bf16x8 vb[4];
#pragma unroll
    for (int nt = 0; nt < 4; ++nt)
      vb[nt] = ld8(&Vb[(size_t)(g * 64 + nt * 16 + l15) * 2048 + k0 + kq * 8]);

    // ---- exp (K pre-scaled: raw v_exp) + DPP 4-head sums + slab ----
#pragma unroll
    for (int qq = 0; qq < 2; ++qq)
#pragma unroll
      for (int ko = 0; ko < 2; ++ko)
#pragma unroll
        for (int r = 0; r < 4; ++r)
          sc[qq][ko][r] = fexp2(sc[qq][ko][r]);
#pragma unroll
    for (int qq = 0; qq < 2; ++qq)
#pragma unroll
      for (int ko = 0; ko < 2; ++ko)
#pragma unroll
        for (int r = 0; r < 4; ++r) {
          float su = hsum4(sc[qq][ko][r]);
          if (hl == 0)
            slab[g * 528 + (zd * 8 + qq * 4 + qr) * 33 + ko * 16 + kq * 4 + r] = su;
        }

    barrier_lgkm();  // B1

    if (tid < 512) {
      int q = tid >> 5, k = tid & 31;
      float s = 0.f;
#pragma unroll
      for (int gg = 0; gg < 8; ++gg) s += slab[gg * 528 + q * 33 + k];
      rsb[q * 36 + k] = __builtin_amdgcn_rcpf(s);
    }

    barrier_lgkm();  // B2

    // ---- pack P (cvt_pk) + PV ----
#pragma unroll
    for (int qq = 0; qq < 2; ++qq) {
      const int ql = zd * 8 + qq * 4 + qr;
      f32x4 rs0 = *(const f32x4*)&rsb[ql * 36 + kq * 4];
      f32x4 rs1 = *(const f32x4*)&rsb[ql * 36 + 16 + kq * 4];
      u32 paw[4];
#pragma unroll
      for (int r = 0; r < 4; ++r)
        paw[r] = cvtpk(sc[qq][0][r] * rs0[r], sc[qq][1][r] * rs1[r]);
      bf16x8 pa = __builtin_bit_cast(bf16x8, *(uint4*)paw);
#pragma unroll
      for (int nt = 0; nt < 4; ++nt)
        acc[qq][nt] = __builtin_amdgcn_mfma_f32_16x16x32_bf16(pa, vb[nt], acc[qq][nt], 0, 0, 0);
    }
  };

  for (int k0 = 0; k0 < 2048; k0 += 64) {
    tilestep(k0, kfA, kfB);
    tilestep(k0 + 32, kfB, kfA);
  }

  // ---- epilogue ----
#pragma unroll
  for (int qq = 0; qq < 2; ++qq)
#pragma unroll
    for (int nt = 0; nt < 4; ++nt)
#pragma unroll
      for (int r = 0; r < 4; ++r)
        O[(size_t)(b * 2048 + qbase + qq * 4 + r) * 2048 +
          (g + 8 * kq) * 64 + nt * 16 + l15] = f2bf(acc[qq][nt][r]);
}

// ---------------- launcher ----------------
extern "C" void kernel_launch(void* const* d_in, const int* in_sizes, int n_in,
                              void* d_out, int out_size, void* d_ws, size_t ws_size,
                              hipStream_t stream) {
  (void)in_sizes; (void)n_in; (void)out_size; (void)ws_size;
  const float* x    = (const float*)d_in[0];
  const float* wq_w = (const float*)d_in[1];
  const float* wq_b = (const float*)d_in[2];
  const float* wk_w = (const float*)d_in[3];
  const float* wk_b = (const float*)d_in[4];
  const float* wv_w = (const float*)d_in[5];
  const float* wv_b = (const float*)d_in[6];
  const float* wo_w = (const float*)d_in[7];
  const float* wo_b = (const float*)d_in[8];
  float* out = (float*)d_out;

  char* p = (char*)d_ws;
  u16* xb  = (u16*)p; p += (size_t)4096 * 2048 * 2;
  u16* wqb = (u16*)p; p += (size_t)2048 * 2048 * 2;
  u16* wkb = (u16*)p; p += (size_t)512 * 2048 * 2;
  u16* wvb = (u16*)p; p += (size_t)512 * 2048 * 2;
  u16* wob = (u16*)p; p += (size_t)2048 * 2048 * 2;
  u16* Qb  = (u16*)p; p += (size_t)4096 * 2048 * 2;
  u16* Kb  = (u16*)p; p += (size_t)4096 * 512 * 2;
  u16* Vtb = (u16*)p; p += (size_t)1024 * 2048 * 2;
  u16* Ob  = (u16*)p; p += (size_t)4096 * 2048 * 2;

  hipLaunchKernelGGL(cvt_all, dim3(2048), dim3(256), 0, stream,
                     x, wq_w, wk_w, wv_w, wo_w, xb, wqb, wkb, wvb, wob);

  // QK scale folded into K projection: 0.125 * log2(e)
  const float kscale = 0.125f * 1.44269504f;
  hipLaunchKernelGGL((gemm_bt<0>), dim3(16, 32), dim3(256), 0, stream,
                     xb, wqb, wq_b, Qb, (float*)nullptr, 2048, 1.0f);
  hipLaunchKernelGGL((gemm_bt<0>), dim3(4, 32),  dim3(256), 0, stream,
                     xb, wkb, wk_b, Kb, (float*)nullptr, 512, kscale);
  hipLaunchKernelGGL((gemm_bt<2>), dim3(4, 32),  dim3(256), 0, stream,
                     xb, wvb, wv_b, Vtb, (float*)nullptr, 512, 1.0f);

  hipLaunchKernelGGL(attn_fused, dim3(256), dim3(1024), 0, stream, Qb, Kb, Vtb, Ob);

  hipLaunchKernelGGL((gemm_bt<1>), dim3(16, 32), dim3(256), 0, stream,
                     Ob, wob, wo_b, (u16*)nullptr, out, 2048, 1.0f);
}

// Round 6
// 427.731 us; speedup vs baseline: 1.1085x; 1.1085x over previous
//
#include <hip/hip_runtime.h>

// GQA (B=2,S=2048,E=2048,H=32,G=8,D=64), softmax over HEAD axis.
// R6: R5 dataflow, but attn block split 1024->512 threads (8 waves = 8 g),
// 8 q-rows/block, grid 512 = 2 blocks/CU (TLP hides barrier stalls; the two
// q-halves of an R5 block never communicated). Explicit named K frags
// (no lambda refs) to avoid the R5 spill (marker: WRITE_SIZE ~= 16.4 MB).

typedef unsigned short u16;
typedef unsigned int u32;
typedef __attribute__((ext_vector_type(8))) __bf16 bf16x8;
typedef __attribute__((ext_vector_type(4))) float f32x4;
typedef __attribute__((ext_vector_type(4))) float float4_t;

#define GLD16(ldsp, gp)                                                  \
  __builtin_amdgcn_global_load_lds(                                      \
      (__attribute__((address_space(1))) void*)(void*)(gp),              \
      (__attribute__((address_space(3))) void*)(void*)(ldsp), 16, 0, 0)

static __device__ __forceinline__ u16 f2bf(float f) {
  union { float f; u32 u; } v; v.f = f;
  u32 u = v.u;
  u32 r = (u + 0x7fffu + ((u >> 16) & 1u)) >> 16;  // RNE
  return (u16)r;
}

static __device__ __forceinline__ bf16x8 ld8(const u16* p) {
  return *(const bf16x8*)p;
}

#if __has_builtin(__builtin_amdgcn_exp2f)
static __device__ __forceinline__ float fexp2(float x) {
  return __builtin_amdgcn_exp2f(x);
}
#else
static __device__ __forceinline__ float fexp2(float x) {
  float r;
  asm("v_exp_f32 %0, %1\n\ts_nop 0" : "=v"(r) : "v"(x));
  return r;
}
#endif

static __device__ __forceinline__ u32 cvtpk(float a, float b) {
  u32 r;
  asm("v_cvt_pk_bf16_f32 %0, %1, %2" : "=v"(r) : "v"(a), "v"(b));
  return r;
}

// barrier that does NOT drain vmcnt (global prefetch stays in flight)
static __device__ __forceinline__ void barrier_lgkm() {
  asm volatile("s_waitcnt lgkmcnt(0)" ::: "memory");
  __builtin_amdgcn_s_barrier();
  asm volatile("" ::: "memory");
}

// sum over the 4 stride-4 lanes within each 16-lane row (head levels)
static __device__ __forceinline__ float hsum4(float v) {
  v += __builtin_bit_cast(float, __builtin_amdgcn_update_dpp(
           0, __builtin_bit_cast(int, v), 0x124, 0xf, 0xf, true));  // row_ror:4
  v += __builtin_bit_cast(float, __builtin_amdgcn_update_dpp(
           0, __builtin_bit_cast(int, v), 0x128, 0xf, 0xf, true));  // row_ror:8
  return v;
}

// ---------------- fused fp32 -> bf16 for all 5 tensors ----------------
__global__ void cvt_all(const float* __restrict__ x, const float* __restrict__ wq,
                        const float* __restrict__ wk, const float* __restrict__ wv,
                        const float* __restrict__ wo, u16* __restrict__ xb,
                        u16* __restrict__ wqb, u16* __restrict__ wkb,
                        u16* __restrict__ wvb, u16* __restrict__ wob) {
  int i = blockIdx.x * blockDim.x + threadIdx.x;
  const int stride = gridDim.x * blockDim.x;
  for (; i < 2359296; i += stride) {
    const float* src;
    u16* dst;
    int j;
    if (i < 1048576)      { src = x;  dst = xb;  j = i; }
    else if (i < 1572864) { src = wq; dst = wqb; j = i - 1048576; }
    else if (i < 1703936) { src = wk; dst = wkb; j = i - 1572864; }
    else if (i < 1835008) { src = wv; dst = wvb; j = i - 1703936; }
    else                  { src = wo; dst = wob; j = i - 1835008; }
    const float4_t* p = (const float4_t*)src + (size_t)j * 2;
    float4_t a = p[0], b = p[1];
    u32 w0 = (u32)f2bf(a[0]) | ((u32)f2bf(a[1]) << 16);
    u32 w1 = (u32)f2bf(a[2]) | ((u32)f2bf(a[3]) << 16);
    u32 w2 = (u32)f2bf(b[0]) | ((u32)f2bf(b[1]) << 16);
    u32 w3 = (u32)f2bf(b[2]) | ((u32)f2bf(b[3]) << 16);
    *(uint4*)(dst + (size_t)j * 8) = make_uint4(w0, w1, w2, w3);
  }
}

// ---------------- GEMM: C[M,N] = (A[M,K] @ W[N,K]^T + bias) * scale --------
template <int MODE>
__global__ __launch_bounds__(256, 2)
void gemm_bt(const u16* __restrict__ A, const u16* __restrict__ Bw,
             const float* __restrict__ bias,
             u16* __restrict__ Cb, float* __restrict__ Cf, int N, float scale) {
  constexpr int K = 2048;
  constexpr int SHSZ = (MODE == 2) ? (128 * 136) : 8192;
  __shared__ u16 sh[SHSZ];
  u16* As = sh;
  u16* Bs = sh + 4096;
  const int tid = threadIdx.x;
  const int lane = tid & 63;
  const int w = tid >> 6;
  const int m0 = blockIdx.y * 128;
  const int n0 = blockIdx.x * 128;
  const int wr = (w >> 1) * 64, wc = (w & 1) * 64;
  const int r15 = lane & 15, kq = lane >> 4;

  f32x4 acc[4][4] = {};

  for (int k0 = 0; k0 < K; k0 += 32) {
#pragma unroll
    for (int i = 0; i < 2; ++i) {
      int c = i * 256 + tid;
      int r = c >> 2, ch = c & 3;
      int sc = (ch ^ (r & 3)) * 8;
      GLD16(&As[c * 8], &A[(size_t)(m0 + r) * K + k0 + sc]);
      GLD16(&Bs[c * 8], &Bw[(size_t)(n0 + r) * K + k0 + sc]);
    }
    __syncthreads();
    bf16x8 af[4], bfr[4];
#pragma unroll
    for (int mt = 0; mt < 4; ++mt) {
      int r = wr + mt * 16 + r15;
      af[mt] = ld8(&As[r * 32 + ((kq ^ (r15 & 3)) * 8)]);
    }
#pragma unroll
    for (int nt = 0; nt < 4; ++nt) {
      int r = wc + nt * 16 + r15;
      bfr[nt] = ld8(&Bs[r * 32 + ((kq ^ (r15 & 3)) * 8)]);
    }
#pragma unroll
    for (int mt = 0; mt < 4; ++mt)
#pragma unroll
      for (int nt = 0; nt < 4; ++nt)
        acc[mt][nt] = __builtin_amdgcn_mfma_f32_16x16x32_bf16(af[mt], bfr[nt], acc[mt][nt], 0, 0, 0);
    __syncthreads();
  }

  if constexpr (MODE == 2) {
#pragma unroll
    for (int mt = 0; mt < 4; ++mt)
#pragma unroll
      for (int nt = 0; nt < 4; ++nt) {
        int col = wc + nt * 16 + r15;
        float bv = bias[n0 + col];
#pragma unroll
        for (int r = 0; r < 4; ++r) {
          int row = wr + mt * 16 + kq * 4 + r;
          sh[col * 136 + row] = f2bf(acc[mt][nt][r] + bv);
        }
      }
    __syncthreads();
    const int m0l = m0 & 2047;
    const int bb = m0 >> 11;
#pragma unroll
    for (int i = 0; i < 8; ++i) {
      int c = i * 256 + tid;
      int cc = c >> 4, so = c & 15;
      int X = cc * 136 + (so >> 2) * 32 + (so & 3) * 4;
      u32 A0 = *(const u32*)&sh[X + 0];
      u32 A1 = *(const u32*)&sh[X + 2];
      u32 B0 = *(const u32*)&sh[X + 16];
      u32 B1 = *(const u32*)&sh[X + 18];
      u32 w0 = __builtin_amdgcn_perm(B0, A0, 0x05040100u);
      u32 w1 = __builtin_amdgcn_perm(B0, A0, 0x07060302u);
      u32 w2 = __builtin_amdgcn_perm(B1, A1, 0x05040100u);
      u32 w3 = __builtin_amdgcn_perm(B1, A1, 0x07060302u);
      *(uint4*)&Cb[(size_t)(bb * 512 + n0 + cc) * 2048 + m0l + so * 8] =
          make_uint4(w0, w1, w2, w3);
    }
  } else {
    const int rb = kq * 4;
#pragma unroll
    for (int mt = 0; mt < 4; ++mt) {
#pragma unroll
      for (int nt = 0; nt < 4; ++nt) {
        int col = n0 + wc + nt * 16 + r15;
        float bv = bias[col];
#pragma unroll
        for (int r = 0; r < 4; ++r) {
          int row = m0 + wr + mt * 16 + rb + r;
          float v = (acc[mt][nt][r] + bv) * scale;
          if constexpr (MODE == 0) Cb[(size_t)row * N + col] = f2bf(v);
          else                     Cf[(size_t)row * N + col] = v;
        }
      }
    }
  }
}

// ---------------- fused attention (R6) ----------------
// Block = 512 thr (8 waves, wave = group g), 8 q-rows. Grid 512 = 2 blk/CU.
// Per 32-k tile: QK mfma(K,Q) [K pre-scaled 0.125*log2e] -> prefetch next K
// + this V -> v_exp -> DPP 4-head sums -> slab | lgkm-B1 | cross-g reduce ->
// rsb | lgkm-B2 | cvt_pk P -> PV mfma.
__global__ __launch_bounds__(512, 4)
void attn_fused(const u16* __restrict__ Q, const u16* __restrict__ Kg,
                const u16* __restrict__ Vt, u16* __restrict__ O) {
  __shared__ float slab[8 * 264];  // [g][q*33 + k], q 0..7
  __shared__ float rsb[8 * 36];    // [q][k] 1/sum

  const int tid = threadIdx.x;
  const int lane = tid & 63, g = tid >> 6;
  const int l15 = lane & 15, kq = lane >> 4;
  const int qr = l15 & 3, hl = l15 >> 2;

  // XCD pinning: batch b -> 4 XCDs (blocks of same b land on same XCDs)
  const int xcd = blockIdx.x & 7;
  const int b = xcd >> 2;
  const int qbase = ((((blockIdx.x >> 3) << 2) + (xcd & 3)) << 3);

  const u16* Qb = Q + (size_t)b * 2048 * 2048;
  const u16* Kb = Kg + (size_t)b * 2048 * 512;
  const u16* Vb = Vt + (size_t)b * 512 * 2048;  // k-interleaved Vt2

  bf16x8 qf[2][2];
#pragma unroll
  for (int qq = 0; qq < 2; ++qq)
#pragma unroll
    for (int t = 0; t < 2; ++t)
      qf[qq][t] = ld8(&Qb[(size_t)(qbase + qq * 4 + qr) * 2048 +
                          (g + 8 * hl) * 64 + t * 32 + kq * 8]);

  f32x4 acc[2][4] = {};

  const u16* kbase = &Kb[(size_t)l15 * 512 + g * 64 + kq * 8];
  const u16* vbase = &Vb[(size_t)(g * 64 + l15) * 2048 + kq * 8];

  bf16x8 cA0, cA1, cB0, cB1;  // current K frags [ko][t]
  bf16x8 nA0, nA1, nB0, nB1;  // next K frags
  cA0 = ld8(kbase + 0 * 512 * 16 + 0);
  cA1 = ld8(kbase + 0 * 512 * 16 + 32);
  cB0 = ld8(kbase + 1 * 512 * 16 + 0);
  cB1 = ld8(kbase + 1 * 512 * 16 + 32);

#define ATTN_TILE(K0, c0, c1, c2, c3, n0_, n1_, n2_, n3_)                      \
  {                                                                            \
    f32x4 s00 = {}, s01 = {}, s10 = {}, s11 = {};                              \
    s00 = __builtin_amdgcn_mfma_f32_16x16x32_bf16(c0, qf[0][0], s00, 0, 0, 0); \
    s00 = __builtin_amdgcn_mfma_f32_16x16x32_bf16(c1, qf[0][1], s00, 0, 0, 0); \
    s01 = __builtin_amdgcn_mfma_f32_16x16x32_bf16(c2, qf[0][0], s01, 0, 0, 0); \
    s01 = __builtin_amdgcn_mfma_f32_16x16x32_bf16(c3, qf[0][1], s01, 0, 0, 0); \
    s10 = __builtin_amdgcn_mfma_f32_16x16x32_bf16(c0, qf[1][0], s10, 0, 0, 0); \
    s10 = __builtin_amdgcn_mfma_f32_16x16x32_bf16(c1, qf[1][1], s10, 0, 0, 0); \
    s11 = __builtin_amdgcn_mfma_f32_16x16x32_bf16(c2, qf[1][0], s11, 0, 0, 0); \
    s11 = __builtin_amdgcn_mfma_f32_16x16x32_bf16(c3, qf[1][1], s11, 0, 0, 0); \
    const int kn = ((K0) + 32) & 2047;                                         \
    n0_ = ld8(kbase + (size_t)kn * 512 + 0);                                   \
    n1_ = ld8(kbase + (size_t)kn * 512 + 32);                                  \
    n2_ = ld8(kbase + (size_t)(kn + 16) * 512 + 0);                            \
    n3_ = ld8(kbase + (size_t)(kn + 16) * 512 + 32);                           \
    bf16x8 vb[4];                                                              \
    _Pragma("unroll") for (int nt = 0; nt < 4; ++nt)                           \
        vb[nt] = ld8(vbase + (size_t)nt * 16 * 2048 + (K0));                   \
    _Pragma("unroll") for (int r = 0; r < 4; ++r) {                            \
      s00[r] = fexp2(s00[r]); s01[r] = fexp2(s01[r]);                          \
      s10[r] = fexp2(s10[r]); s11[r] = fexp2(s11[r]);                          \
    }                                                                          \
    _Pragma("unroll") for (int r = 0; r < 4; ++r) {                            \
      float u00 = hsum4(s00[r]), u01 = hsum4(s01[r]);                          \
      float u10 = hsum4(s10[r]), u11 = hsum4(s11[r]);                          \
      if (hl == 0) {                                                           \
        slab[g * 264 + (0 + qr) * 33 + 0 + kq * 4 + r] = u00;                  \
        slab[g * 264 + (0 + qr) * 33 + 16 + kq * 4 + r] = u01;                 \
        slab[g * 264 + (4 + qr) * 33 + 0 + kq * 4 + r] = u10;                  \
        slab[g * 264 + (4 + qr) * 33 + 16 + kq * 4 + r] = u11;                 \
      }                                                                        \
    }                                                                          \
    barrier_lgkm();                                                            \
    if (tid < 256) {                                                           \
      int q = tid >> 5, k = tid & 31;                                          \
      float s = 0.f;                                                           \
      _Pragma("unroll") for (int gg = 0; gg < 8; ++gg)                         \
          s += slab[gg * 264 + q * 33 + k];                                    \
      rsb[q * 36 + k] = __builtin_amdgcn_rcpf(s);                              \
    }                                                                          \
    barrier_lgkm();                                                            \
    {                                                                          \
      f32x4 r00 = *(const f32x4*)&rsb[(0 + qr) * 36 + kq * 4];                 \
      f32x4 r01 = *(const f32x4*)&rsb[(0 + qr) * 36 + 16 + kq * 4];            \
      f32x4 r10 = *(const f32x4*)&rsb[(4 + qr) * 36 + kq * 4];                 \
      f32x4 r11 = *(const f32x4*)&rsb[(4 + qr) * 36 + 16 + kq * 4];            \
      u32 paw[4];                                                              \
      _Pragma("unroll") for (int r = 0; r < 4; ++r)                            \
          paw[r] = cvtpk(s00[r] * r00[r], s01[r] * r01[r]);                    \
      bf16x8 pa0 = __builtin_bit_cast(bf16x8, *(uint4*)paw);                   \
      _Pragma("unroll") for (int r = 0; r < 4; ++r)                            \
          paw[r] = cvtpk(s10[r] * r10[r], s11[r] * r11[r]);                    \
      bf16x8 pa1 = __builtin_bit_cast(bf16x8, *(uint4*)paw);                   \
      _Pragma("unroll") for (int nt = 0; nt < 4; ++nt) {                       \
        acc[0][nt] = __builtin_amdgcn_mfma_f32_16x16x32_bf16(pa0, vb[nt],      \
                                                             acc[0][nt], 0, 0, 0); \
        acc[1][nt] = __builtin_amdgcn_mfma_f32_16x16x32_bf16(pa1, vb[nt],      \
                                                             acc[1][nt], 0, 0, 0); \
      }                                                                        \
    }                                                                          \
  }

  for (int k0 = 0; k0 < 2048; k0 += 64) {
    ATTN_TILE(k0, cA0, cA1, cB0, cB1, nA0, nA1, nB0, nB1);
    ATTN_TILE(k0 + 32, nA0, nA1, nB0, nB1, cA0, cA1, cB0, cB1);
  }
#undef ATTN_TILE

  // ---- epilogue: row kq*4+r -> (h-level kq, q-row r) ----
#pragma unroll
  for (int qq = 0; qq < 2; ++qq)
#pragma unroll
    for (int nt = 0; nt < 4; ++nt)
#pragma unroll
      for (int r = 0; r < 4; ++r)
        O[(size_t)(b * 2048 + qbase + qq * 4 + r) * 2048 +
          (g + 8 * kq) * 64 + nt * 16 + l15] = f2bf(acc[qq][nt][r]);
}

// ---------------- launcher ----------------
extern "C" void kernel_launch(void* const* d_in, const int* in_sizes, int n_in,
                              void* d_out, int out_size, void* d_ws, size_t ws_size,
                              hipStream_t stream) {
  (void)in_sizes; (void)n_in; (void)out_size; (void)ws_size;
  const float* x    = (const float*)d_in[0];
  const float* wq_w = (const float*)d_in[1];
  const float* wq_b = (const float*)d_in[2];
  const float* wk_w = (const float*)d_in[3];
  const float* wk_b = (const float*)d_in[4];
  const float* wv_w = (const float*)d_in[5];
  const float* wv_b = (const float*)d_in[6];
  const float* wo_w = (const float*)d_in[7];
  const float* wo_b = (const float*)d_in[8];
  float* out = (float*)d_out;

  char* p = (char*)d_ws;
  u16* xb  = (u16*)p; p += (size_t)4096 * 2048 * 2;
  u16* wqb = (u16*)p; p += (size_t)2048 * 2048 * 2;
  u16* wkb = (u16*)p; p += (size_t)512 * 2048 * 2;
  u16* wvb = (u16*)p; p += (size_t)512 * 2048 * 2;
  u16* wob = (u16*)p; p += (size_t)2048 * 2048 * 2;
  u16* Qb  = (u16*)p; p += (size_t)4096 * 2048 * 2;
  u16* Kb  = (u16*)p; p += (size_t)4096 * 512 * 2;
  u16* Vtb = (u16*)p; p += (size_t)1024 * 2048 * 2;
  u16* Ob  = (u16*)p; p += (size_t)4096 * 2048 * 2;

  hipLaunchKernelGGL(cvt_all, dim3(2048), dim3(256), 0, stream,
                     x, wq_w, wk_w, wv_w, wo_w, xb, wqb, wkb, wvb, wob);

  const float kscale = 0.125f * 1.44269504f;  // fold 1/sqrt(D) * log2(e) into K
  hipLaunchKernelGGL((gemm_bt<0>), dim3(16, 32), dim3(256), 0, stream,
                     xb, wqb, wq_b, Qb, (float*)nullptr, 2048, 1.0f);
  hipLaunchKernelGGL((gemm_bt<0>), dim3(4, 32),  dim3(256), 0, stream,
                     xb, wkb, wk_b, Kb, (float*)nullptr, 512, kscale);
  hipLaunchKernelGGL((gemm_bt<2>), dim3(4, 32),  dim3(256), 0, stream,
                     xb, wvb, wv_b, Vtb, (float*)nullptr, 512, 1.0f);

  hipLaunchKernelGGL(attn_fused, dim3(512), dim3(512), 0, stream, Qb, Kb, Vtb, Ob);

  hipLaunchKernelGGL((gemm_bt<1>), dim3(16, 32), dim3(256), 0, stream,
                     Ob, wob, wo_b, (u16*)nullptr, out, 2048, 1.0f);
}

// Round 9
// 418.223 us; speedup vs baseline: 1.1337x; 1.0227x over previous
//
#include <hip/hip_runtime.h>

// GQA (B=2,S=2048,E=2048,H=32,G=8,D=64), softmax over HEAD axis.
// R9 = R6 (last passing config) with ONE change: attn __launch_bounds__
// (512,4) -> (512,2). Evidence: VGPR_Count=64 + WRITE_SIZE 21.5MB (output is
// 16.4MB) across R4-R6 matches CUDA blocks/CU semantics for the 2nd arg
// (4 blocks * 8 waves = 8 waves/SIMD -> 64-VGPR cap -> spill). (512,2) gives
// a 128-VGPR cap for the ~120-reg working set. [R7/R8 2-pass: reverted —
// failed twice with paper-correct layouts; do not retry without a probe.]

typedef unsigned short u16;
typedef unsigned int u32;
typedef __attribute__((ext_vector_type(8))) __bf16 bf16x8;
typedef __attribute__((ext_vector_type(4))) float f32x4;
typedef __attribute__((ext_vector_type(4))) float float4_t;

#define GLD16(ldsp, gp)                                                  \
  __builtin_amdgcn_global_load_lds(                                      \
      (__attribute__((address_space(1))) void*)(void*)(gp),              \
      (__attribute__((address_space(3))) void*)(void*)(ldsp), 16, 0, 0)

static __device__ __forceinline__ u16 f2bf(float f) {
  union { float f; u32 u; } v; v.f = f;
  u32 u = v.u;
  u32 r = (u + 0x7fffu + ((u >> 16) & 1u)) >> 16;  // RNE
  return (u16)r;
}

static __device__ __forceinline__ bf16x8 ld8(const u16* p) {
  return *(const bf16x8*)p;
}

#if __has_builtin(__builtin_amdgcn_exp2f)
static __device__ __forceinline__ float fexp2(float x) {
  return __builtin_amdgcn_exp2f(x);
}
#else
static __device__ __forceinline__ float fexp2(float x) {
  float r;
  asm("v_exp_f32 %0, %1\n\ts_nop 0" : "=v"(r) : "v"(x));
  return r;
}
#endif

static __device__ __forceinline__ u32 cvtpk(float a, float b) {
  u32 r;
  asm("v_cvt_pk_bf16_f32 %0, %1, %2" : "=v"(r) : "v"(a), "v"(b));
  return r;
}

// barrier that does NOT drain vmcnt (global prefetch stays in flight)
static __device__ __forceinline__ void barrier_lgkm() {
  asm volatile("s_waitcnt lgkmcnt(0)" ::: "memory");
  __builtin_amdgcn_s_barrier();
  asm volatile("" ::: "memory");
}

// sum over the 4 stride-4 lanes within each 16-lane row (head levels)
static __device__ __forceinline__ float hsum4(float v) {
  v += __builtin_bit_cast(float, __builtin_amdgcn_update_dpp(
           0, __builtin_bit_cast(int, v), 0x124, 0xf, 0xf, true));  // row_ror:4
  v += __builtin_bit_cast(float, __builtin_amdgcn_update_dpp(
           0, __builtin_bit_cast(int, v), 0x128, 0xf, 0xf, true));  // row_ror:8
  return v;
}

// ---------------- fused fp32 -> bf16 for all 5 tensors ----------------
__global__ void cvt_all(const float* __restrict__ x, const float* __restrict__ wq,
                        const float* __restrict__ wk, const float* __restrict__ wv,
                        const float* __restrict__ wo, u16* __restrict__ xb,
                        u16* __restrict__ wqb, u16* __restrict__ wkb,
                        u16* __restrict__ wvb, u16* __restrict__ wob) {
  int i = blockIdx.x * blockDim.x + threadIdx.x;
  const int stride = gridDim.x * blockDim.x;
  for (; i < 2359296; i += stride) {
    const float* src;
    u16* dst;
    int j;
    if (i < 1048576)      { src = x;  dst = xb;  j = i; }
    else if (i < 1572864) { src = wq; dst = wqb; j = i - 1048576; }
    else if (i < 1703936) { src = wk; dst = wkb; j = i - 1572864; }
    else if (i < 1835008) { src = wv; dst = wvb; j = i - 1703936; }
    else                  { src = wo; dst = wob; j = i - 1835008; }
    const float4_t* p = (const float4_t*)src + (size_t)j * 2;
    float4_t a = p[0], b = p[1];
    u32 w0 = (u32)f2bf(a[0]) | ((u32)f2bf(a[1]) << 16);
    u32 w1 = (u32)f2bf(a[2]) | ((u32)f2bf(a[3]) << 16);
    u32 w2 = (u32)f2bf(b[0]) | ((u32)f2bf(b[1]) << 16);
    u32 w3 = (u32)f2bf(b[2]) | ((u32)f2bf(b[3]) << 16);
    *(uint4*)(dst + (size_t)j * 8) = make_uint4(w0, w1, w2, w3);
  }
}

// ---------------- GEMM: C[M,N] = (A[M,K] @ W[N,K]^T + bias) * scale --------
template <int MODE>
__global__ __launch_bounds__(256, 2)
void gemm_bt(const u16* __restrict__ A, const u16* __restrict__ Bw,
             const float* __restrict__ bias,
             u16* __restrict__ Cb, float* __restrict__ Cf, int N, float scale) {
  constexpr int K = 2048;
  constexpr int SHSZ = (MODE == 2) ? (128 * 136) : 8192;
  __shared__ u16 sh[SHSZ];
  u16* As = sh;
  u16* Bs = sh + 4096;
  const int tid = threadIdx.x;
  const int lane = tid & 63;
  const int w = tid >> 6;
  const int m0 = blockIdx.y * 128;
  const int n0 = blockIdx.x * 128;
  const int wr = (w >> 1) * 64, wc = (w & 1) * 64;
  const int r15 = lane & 15, kq = lane >> 4;

  f32x4 acc[4][4] = {};

  for (int k0 = 0; k0 < K; k0 += 32) {
#pragma unroll
    for (int i = 0; i < 2; ++i) {
      int c = i * 256 + tid;
      int r = c >> 2, ch = c & 3;
      int sc = (ch ^ (r & 3)) * 8;
      GLD16(&As[c * 8], &A[(size_t)(m0 + r) * K + k0 + sc]);
      GLD16(&Bs[c * 8], &Bw[(size_t)(n0 + r) * K + k0 + sc]);
    }
    __syncthreads();
    bf16x8 af[4], bfr[4];
#pragma unroll
    for (int mt = 0; mt < 4; ++mt) {
      int r = wr + mt * 16 + r15;
      af[mt] = ld8(&As[r * 32 + ((kq ^ (r15 & 3)) * 8)]);
    }
#pragma unroll
    for (int nt = 0; nt < 4; ++nt) {
      int r = wc + nt * 16 + r15;
      bfr[nt] = ld8(&Bs[r * 32 + ((kq ^ (r15 & 3)) * 8)]);
    }
#pragma unroll
    for (int mt = 0; mt < 4; ++mt)
#pragma unroll
      for (int nt = 0; nt < 4; ++nt)
        acc[mt][nt] = __builtin_amdgcn_mfma_f32_16x16x32_bf16(af[mt], bfr[nt], acc[mt][nt], 0, 0, 0);
    __syncthreads();
  }

  if constexpr (MODE == 2) {
#pragma unroll
    for (int mt = 0; mt < 4; ++mt)
#pragma unroll
      for (int nt = 0; nt < 4; ++nt) {
        int col = wc + nt * 16 + r15;
        float bv = bias[n0 + col];
#pragma unroll
        for (int r = 0; r < 4; ++r) {
          int row = wr + mt * 16 + kq * 4 + r;
          sh[col * 136 + row] = f2bf(acc[mt][nt][r] + bv);
        }
      }
    __syncthreads();
    const int m0l = m0 & 2047;
    const int bb = m0 >> 11;
#pragma unroll
    for (int i = 0; i < 8; ++i) {
      int c = i * 256 + tid;
      int cc = c >> 4, so = c & 15;
      int X = cc * 136 + (so >> 2) * 32 + (so & 3) * 4;
      u32 A0 = *(const u32*)&sh[X + 0];
      u32 A1 = *(const u32*)&sh[X + 2];
      u32 B0 = *(const u32*)&sh[X + 16];
      u32 B1 = *(const u32*)&sh[X + 18];
      u32 w0 = __builtin_amdgcn_perm(B0, A0, 0x05040100u);
      u32 w1 = __builtin_amdgcn_perm(B0, A0, 0x07060302u);
      u32 w2 = __builtin_amdgcn_perm(B1, A1, 0x05040100u);
      u32 w3 = __builtin_amdgcn_perm(B1, A1, 0x07060302u);
      *(uint4*)&Cb[(size_t)(bb * 512 + n0 + cc) * 2048 + m0l + so * 8] =
          make_uint4(w0, w1, w2, w3);
    }
  } else {
    const int rb = kq * 4;
#pragma unroll
    for (int mt = 0; mt < 4; ++mt) {
#pragma unroll
      for (int nt = 0; nt < 4; ++nt) {
        int col = n0 + wc + nt * 16 + r15;
        float bv = bias[col];
#pragma unroll
        for (int r = 0; r < 4; ++r) {
          int row = m0 + wr + mt * 16 + rb + r;
          float v = (acc[mt][nt][r] + bv) * scale;
          if constexpr (MODE == 0) Cb[(size_t)row * N + col] = f2bf(v);
          else                     Cf[(size_t)row * N + col] = v;
        }
      }
    }
  }
}

// ---------------- fused attention (R9 = R6 + correct launch bounds) --------
// Block = 512 thr (8 waves, wave = group g), 8 q-rows. Grid 512 = 2 blk/CU.
// Per 32-k tile: QK mfma(K,Q) [K pre-scaled 0.125*log2e] -> prefetch next K
// + this V -> v_exp -> DPP 4-head sums -> slab | lgkm-B1 | cross-g reduce ->
// rsb | lgkm-B2 | cvt_pk P -> PV mfma.
// launch_bounds 2nd arg = min BLOCKS/CU (CUDA semantics observed on this
// toolchain): (512,2) -> 4 waves/SIMD -> 128-VGPR cap, no spill.
__global__ __launch_bounds__(512, 2)
void attn_fused(const u16* __restrict__ Q, const u16* __restrict__ Kg,
                const u16* __restrict__ Vt, u16* __restrict__ O) {
  __shared__ float slab[8 * 264];  // [g][q*33 + k], q 0..7
  __shared__ float rsb[8 * 36];    // [q][k] 1/sum

  const int tid = threadIdx.x;
  const int lane = tid & 63, g = tid >> 6;
  const int l15 = lane & 15, kq = lane >> 4;
  const int qr = l15 & 3, hl = l15 >> 2;

  // XCD pinning: batch b -> 4 XCDs (blocks of same b land on same XCDs)
  const int xcd = blockIdx.x & 7;
  const int b = xcd >> 2;
  const int qbase = ((((blockIdx.x >> 3) << 2) + (xcd & 3)) << 3);

  const u16* Qb = Q + (size_t)b * 2048 * 2048;
  const u16* Kb = Kg + (size_t)b * 2048 * 512;
  const u16* Vb = Vt + (size_t)b * 512 * 2048;  // k-interleaved Vt2

  bf16x8 qf[2][2];
#pragma unroll
  for (int qq = 0; qq < 2; ++qq)
#pragma unroll
    for (int t = 0; t < 2; ++t)
      qf[qq][t] = ld8(&Qb[(size_t)(qbase + qq * 4 + qr) * 2048 +
                          (g + 8 * hl) * 64 + t * 32 + kq * 8]);

  f32x4 acc[2][4] = {};

  const u16* kbase = &Kb[(size_t)l15 * 512 + g * 64 + kq * 8];
  const u16* vbase = &Vb[(size_t)(g * 64 + l15) * 2048 + kq * 8];

  bf16x8 cA0, cA1, cB0, cB1;  // current K frags [ko][t]
  bf16x8 nA0, nA1, nB0, nB1;  // next K frags
  cA0 = ld8(kbase + 0 * 512 * 16 + 0);
  cA1 = ld8(kbase + 0 * 512 * 16 + 32);
  cB0 = ld8(kbase + 1 * 512 * 16 + 0);
  cB1 = ld8(kbase + 1 * 512 * 16 + 32);

#define ATTN_TILE(K0, c0, c1, c2, c3, n0_, n1_, n2_, n3_)                      \
  {                                                                            \
    f32x4 s00 = {}, s01 = {}, s10 = {}, s11 = {};                              \
    s00 = __builtin_amdgcn_mfma_f32_16x16x32_bf16(c0, qf[0][0], s00, 0, 0, 0); \
    s00 = __builtin_amdgcn_mfma_f32_16x16x32_bf16(c1, qf[0][1], s00, 0, 0, 0); \
    s01 = __builtin_amdgcn_mfma_f32_16x16x32_bf16(c2, qf[0][0], s01, 0, 0, 0); \
    s01 = __builtin_amdgcn_mfma_f32_16x16x32_bf16(c3, qf[0][1], s01, 0, 0, 0); \
    s10 = __builtin_amdgcn_mfma_f32_16x16x32_bf16(c0, qf[1][0], s10, 0, 0, 0); \
    s10 = __builtin_amdgcn_mfma_f32_16x16x32_bf16(c1, qf[1][1], s10, 0, 0, 0); \
    s11 = __builtin_amdgcn_mfma_f32_16x16x32_bf16(c2, qf[1][0], s11, 0, 0, 0); \
    s11 = __builtin_amdgcn_mfma_f32_16x16x32_bf16(c3, qf[1][1], s11, 0, 0, 0); \
    const int kn = ((K0) + 32) & 2047;                                         \
    n0_ = ld8(kbase + (size_t)kn * 512 + 0);                                   \
    n1_ = ld8(kbase + (size_t)kn * 512 + 32);                                  \
    n2_ = ld8(kbase + (size_t)(kn + 16) * 512 + 0);                            \
    n3_ = ld8(kbase + (size_t)(kn + 16) * 512 + 32);                           \
    bf16x8 vb[4];                                                              \
    _Pragma("unroll") for (int nt = 0; nt < 4; ++nt)                           \
        vb[nt] = ld8(vbase + (size_t)nt * 16 * 2048 + (K0));                   \
    _Pragma("unroll") for (int r = 0; r < 4; ++r) {                            \
      s00[r] = fexp2(s00[r]); s01[r] = fexp2(s01[r]);                          \
      s10[r] = fexp2(s10[r]); s11[r] = fexp2(s11[r]);                          \
    }                                                                          \
    _Pragma("unroll") for (int r = 0; r < 4; ++r) {                            \
      float u00 = hsum4(s00[r]), u01 = hsum4(s01[r]);                          \
      float u10 = hsum4(s10[r]), u11 = hsum4(s11[r]);                          \
      if (hl == 0) {                                                           \
        slab[g * 264 + (0 + qr) * 33 + 0 + kq * 4 + r] = u00;                  \
        slab[g * 264 + (0 + qr) * 33 + 16 + kq * 4 + r] = u01;                 \
        slab[g * 264 + (4 + qr) * 33 + 0 + kq * 4 + r] = u10;                  \
        slab[g * 264 + (4 + qr) * 33 + 16 + kq * 4 + r] = u11;                 \
      }                                                                        \
    }                                                                          \
    barrier_lgkm();                                                            \
    if (tid < 256) {                                                           \
      int q = tid >> 5, k = tid & 31;                                          \
      float s = 0.f;                                                           \
      _Pragma("unroll") for (int gg = 0; gg < 8; ++gg)                         \
          s += slab[gg * 264 + q * 33 + k];                                    \
      rsb[q * 36 + k] = __builtin_amdgcn_rcpf(s);                              \
    }                                                                          \
    barrier_lgkm();                                                            \
    {                                                                          \
      f32x4 r00 = *(const f32x4*)&rsb[(0 + qr) * 36 + kq * 4];                 \
      f32x4 r01 = *(const f32x4*)&rsb[(0 + qr) * 36 + 16 + kq * 4];            \
      f32x4 r10 = *(const f32x4*)&rsb[(4 + qr) * 36 + kq * 4];                 \
      f32x4 r11 = *(const f32x4*)&rsb[(4 + qr) * 36 + 16 + kq * 4];            \
      u32 paw[4];                                                              \
      _Pragma("unroll") for (int r = 0; r < 4; ++r)                            \
          paw[r] = cvtpk(s00[r] * r00[r], s01[r] * r01[r]);                    \
      bf16x8 pa0 = __builtin_bit_cast(bf16x8, *(uint4*)paw);                   \
      _Pragma("unroll") for (int r = 0; r < 4; ++r)                            \
          paw[r] = cvtpk(s10[r] * r10[r], s11[r] * r11[r]);                    \
      bf16x8 pa1 = __builtin_bit_cast(bf16x8, *(uint4*)paw);                   \
      _Pragma("unroll") for (int nt = 0; nt < 4; ++nt) {                       \
        acc[0][nt] = __builtin_amdgcn_mfma_f32_16x16x32_bf16(pa0, vb[nt],      \
                                                             acc[0][nt], 0, 0, 0); \
        acc[1][nt] = __builtin_amdgcn_mfma_f32_16x16x32_bf16(pa1, vb[nt],      \
                                                             acc[1][nt], 0, 0, 0); \
      }                                                                        \
    }                                                                          \
  }

  for (int k0 = 0; k0 < 2048; k0 += 64) {
    ATTN_TILE(k0, cA0, cA1, cB0, cB1, nA0, nA1, nB0, nB1);
    ATTN_TILE(k0 + 32, nA0, nA1, nB0, nB1, cA0, cA1, cB0, cB1);
  }
#undef ATTN_TILE

  // ---- epilogue: row kq*4+r -> (h-level kq, q-row r) ----
#pragma unroll
  for (int qq = 0; qq < 2; ++qq)
#pragma unroll
    for (int nt = 0; nt < 4; ++nt)
#pragma unroll
      for (int r = 0; r < 4; ++r)
        O[(size_t)(b * 2048 + qbase + qq * 4 + r) * 2048 +
          (g + 8 * kq) * 64 + nt * 16 + l15] = f2bf(acc[qq][nt][r]);
}

// ---------------- launcher ----------------
extern "C" void kernel_launch(void* const* d_in, const int* in_sizes, int n_in,
                              void* d_out, int out_size, void* d_ws, size_t ws_size,
                              hipStream_t stream) {
  (void)in_sizes; (void)n_in; (void)out_size; (void)ws_size;
  const float* x    = (const float*)d_in[0];
  const float* wq_w = (const float*)d_in[1];
  const float* wq_b = (const float*)d_in[2];
  const float* wk_w = (const float*)d_in[3];
  const float* wk_b = (const float*)d_in[4];
  const float* wv_w = (const float*)d_in[5];
  const float* wv_b = (const float*)d_in[6];
  const float* wo_w = (const float*)d_in[7];
  const float* wo_b = (const float*)d_in[8];
  float* out = (float*)d_out;

  char* p = (char*)d_ws;
  u16* xb  = (u16*)p; p += (size_t)4096 * 2048 * 2;
  u16* wqb = (u16*)p; p += (size_t)2048 * 2048 * 2;
  u16* wkb = (u16*)p; p += (size_t)512 * 2048 * 2;
  u16* wvb = (u16*)p; p += (size_t)512 * 2048 * 2;
  u16* wob = (u16*)p; p += (size_t)2048 * 2048 * 2;
  u16* Qb  = (u16*)p; p += (size_t)4096 * 2048 * 2;
  u16* Kb  = (u16*)p; p += (size_t)4096 * 512 * 2;
  u16* Vtb = (u16*)p; p += (size_t)1024 * 2048 * 2;
  u16* Ob  = (u16*)p; p += (size_t)4096 * 2048 * 2;

  hipLaunchKernelGGL(cvt_all, dim3(2048), dim3(256), 0, stream,
                     x, wq_w, wk_w, wv_w, wo_w, xb, wqb, wkb, wvb, wob);

  const float kscale = 0.125f * 1.44269504f;  // fold 1/sqrt(D) * log2(e) into K
  hipLaunchKernelGGL((gemm_bt<0>), dim3(16, 32), dim3(256), 0, stream,
                     xb, wqb, wq_b, Qb, (float*)nullptr, 2048, 1.0f);
  hipLaunchKernelGGL((gemm_bt<0>), dim3(4, 32),  dim3(256), 0, stream,
                     xb, wkb, wk_b, Kb, (float*)nullptr, 512, kscale);
  hipLaunchKernelGGL((gemm_bt<2>), dim3(4, 32),  dim3(256), 0, stream,
                     xb, wvb, wv_b, Vtb, (float*)nullptr, 512, 1.0f);

  hipLaunchKernelGGL(attn_fused, dim3(512), dim3(512), 0, stream, Qb, Kb, Vtb, Ob);

  hipLaunchKernelGGL((gemm_bt<1>), dim3(16, 32), dim3(256), 0, stream,
                     Ob, wob, wo_b, (u16*)nullptr, out, 2048, 1.0f);
}